// Round 23
// baseline (102.214 us; speedup 1.0000x reference)
//
#include <hip/hip_runtime.h>

// MMoE: B=16384 D=512 U=128 E=16 T=4, fp32 in/out.
// vs r22 (PASSING, 91.3us; moe 57.5 at 2 blocks/CU): trade prefetch depth
// for occupancy — 2 LDS buffers (48KB -> 3 blocks/CU, 24 waves/CU) with
// depth-1 prefetch, ONE vmcnt(0)+s_barrier per K-step (load spans the full
// MFMA phase; cross-block TLP hides the drain). Epilogue -> r16-proven
// two-pass ([64][264]=33.8KB fits 48KB). Same swizzle pair, same K-order
// (bit-identical accumulation), prep r19 VERBATIM.
// ws: gates 4MiB @0, xb 16MiB @4, ekT 2MiB @20.

#define Bsz 16384
#define Dd  512
#define Uu  128
#define Ee  16
#define Tt  4
#define Nn  2048   // U*E

typedef short bf16x8 __attribute__((ext_vector_type(8)));
typedef float f32x4 __attribute__((ext_vector_type(4)));
typedef unsigned short u16x8 __attribute__((ext_vector_type(8)));

static __device__ __forceinline__ unsigned short f2bf(float f) {
    unsigned int u = __builtin_bit_cast(unsigned int, f);
    u += 0x7fffu + ((u >> 16) & 1u);   // round-to-nearest-even
    return (unsigned short)(u >> 16);
}
static __device__ __forceinline__ float bf2f(unsigned short s) {
    return __builtin_bit_cast(float, (unsigned int)s << 16);
}

#define GLOAD16(g, l) __builtin_amdgcn_global_load_lds( \
    (const __attribute__((address_space(1))) void*)(g), \
    (__attribute__((address_space(3))) void*)(l), 16, 0, 0)

// ---------------- Kernel A: prep = gates (+x->xb linear) U convert_ek ----------------
// r19 VERBATIM.
__global__ __launch_bounds__(256) void prep_kernel(
        const float* __restrict__ x, const float* __restrict__ gk,
        const float* __restrict__ gb, const float* __restrict__ ek,
        float* __restrict__ gates, unsigned short* __restrict__ xb,
        unsigned short* __restrict__ ekT) {
    __shared__ __align__(16) char pm[40960];
    const int tid = threadIdx.x;
    if (blockIdx.x >= 1024) {
        unsigned short* ts = (unsigned short*)pm;  // [64*65]
        const int b2 = blockIdx.x - 1024;
        const int n0 = (b2 & 31) * 64, d0 = (b2 >> 5) * 64;
        #pragma unroll
        for (int i = 0; i < 4; ++i) {
            int flat = i * 256 + tid;
            int dl = flat >> 4, ng = (flat & 15) * 4;
            const float4 v = *(const float4*)(ek + (size_t)(d0 + dl) * Nn + n0 + ng);
            ts[(ng + 0) * 65 + dl] = f2bf(v.x);
            ts[(ng + 1) * 65 + dl] = f2bf(v.y);
            ts[(ng + 2) * 65 + dl] = f2bf(v.z);
            ts[(ng + 3) * 65 + dl] = f2bf(v.w);
        }
        __syncthreads();
        #pragma unroll
        for (int i = 0; i < 4; ++i) {
            int flat = i * 256 + tid;
            int nl = flat >> 4, dg = (flat & 15) * 4;
            ushort4 w = make_ushort4(ts[nl * 65 + dg], ts[nl * 65 + dg + 1],
                                     ts[nl * 65 + dg + 2], ts[nl * 65 + dg + 3]);
            *(ushort4*)(ekT + (size_t)(n0 + nl) * Dd + d0 + dg) = w;
        }
        return;
    }
    float (*xl)[128] = (float (*)[128])pm;          // 8 KB
    float (*gkl)[64] = (float (*)[64])(pm + 8192);  // 32 KB
    const int w = tid >> 6, lane = tid & 63;
    const int b0 = blockIdx.x * 16;
    float acc[4] = {0.f, 0.f, 0.f, 0.f};

    for (int c = 0; c < 4; ++c) {
        const int d0 = c * 128;
        __syncthreads();  // previous chunk consumed
        #pragma unroll
        for (int p = 0; p < 2; ++p) {
            const int flat = p * 256 + tid;
            const int row = flat >> 5, c4 = (flat & 31) * 4;
            const float4 v =
                *(const float4*)(x + (size_t)(b0 + row) * Dd + d0 + c4);
            *(float4*)(&xl[row][c4]) = v;
            *(ushort4*)(xb + (size_t)(b0 + row) * Dd + d0 + c4) =
                make_ushort4(f2bf(v.x), f2bf(v.y), f2bf(v.z), f2bf(v.w));
        }
        {
            const int n = tid & 63, dl0 = tid >> 6;
            const float* gp = gk + (size_t)(n >> 4) * (Dd * Ee) + (n & 15)
                                 + (size_t)(d0 + dl0) * Ee;
            #pragma unroll
            for (int j = 0; j < 32; ++j)
                gkl[dl0 + j * 4][n] = gp[(size_t)j * 4 * Ee];
        }
        __syncthreads();
        #pragma unroll 4
        for (int dq = 0; dq < 32; ++dq) {
            float wv[4];
            #pragma unroll
            for (int q = 0; q < 4; ++q) wv[q] = gkl[dq * 4 + q][lane];
            #pragma unroll
            for (int r = 0; r < 4; ++r) {
                const float4 xv = *(const float4*)(&xl[w * 4 + r][dq * 4]);
                float a = acc[r];
                a = fmaf(xv.x, wv[0], a);
                a = fmaf(xv.y, wv[1], a);
                a = fmaf(xv.z, wv[2], a);
                a = fmaf(xv.w, wv[3], a);
                acc[r] = a;
            }
        }
    }
    const float bias = gb[lane];
    #pragma unroll
    for (int r = 0; r < 4; ++r) {
        float a = acc[r] + bias;
        float m = a;
        m = fmaxf(m, __shfl_xor(m, 1));
        m = fmaxf(m, __shfl_xor(m, 2));
        m = fmaxf(m, __shfl_xor(m, 4));
        m = fmaxf(m, __shfl_xor(m, 8));
        float p = __expf(a - m);
        float s = p;
        s += __shfl_xor(s, 1);
        s += __shfl_xor(s, 2);
        s += __shfl_xor(s, 4);
        s += __shfl_xor(s, 8);
        gates[(size_t)(b0 + w * 4 + r) * 64 + lane] = p / s;  // [b][t*16+e]
    }
}

// ---------------- Kernel B: expert GEMM + relu + gate contraction ----------------
// 128x256, 8 waves, BK=32, DOUBLE-buffer 48KB -> 3 blocks/CU, depth-1.
#define BM 128
#define BN 256
#define BK 32

// src pre-swizzle (r18/r22-PASSED pair): phys chunk p of row r holds logical
// chunk l = p ^ ((r>>2)&3); read uses ph = (lhi ^ (llo>>2))<<4.
#define ST_A(buf, kt_) {                                                        \
    const int c_ = wave * 64 + lane;                                            \
    const int r_ = c_ >> 2;                                                     \
    const int l_ = (c_ & 3) ^ ((r_ >> 2) & 3);                                  \
    GLOAD16(xb + (size_t)(b0 + r_) * Dd + (kt_) * BK + l_ * 8,                  \
            smem + (buf) * 24576 + c_ * 16); }
#define ST_B(buf, kt_) { _Pragma("unroll")                                      \
    for (int i_ = 0; i_ < 2; ++i_) {                                            \
        const int c_ = i_ * 512 + wave * 64 + lane;                             \
        const int r_ = c_ >> 2;                                                 \
        const int l_ = (c_ & 3) ^ ((r_ >> 2) & 3);                              \
        GLOAD16(ekT + (size_t)(n0 + r_) * Dd + (kt_) * BK + l_ * 8,             \
                smem + (buf) * 24576 + 8192 + c_ * 16); } }
#define STAGE(buf, kt_) { ST_A(buf, kt_) ST_B(buf, kt_) }  // 3 loads/wave

__global__ __launch_bounds__(512) void moe_kernel(
        const unsigned short* __restrict__ xb,
        const unsigned short* __restrict__ ekT,
        const float* __restrict__ eb, const float* __restrict__ gates,
        float* __restrict__ out) {
    __shared__ __align__(64) char smem[49152];  // 2 bufs x (A 8K + B 16K)
    const int tid = threadIdx.x;
    const int wave = tid >> 6, lane = tid & 63;
    const int llo = lane & 15, lhi = lane >> 4;
    const int g = (blockIdx.x & 7) * 128 + (blockIdx.x >> 3);  // XCD swizzle
    const int b0 = (g >> 3) * BM;
    const int n0 = (g & 7) * BN;
    const int mr = (wave >> 2) * 64, nc = (wave & 3) * 64;
    const int wr = wave >> 2;
    f32x4 acc[4][4] = {};

    STAGE(0, 0);
    for (int kt = 0; kt < Dd / BK; ++kt) {
        const char* aB = smem + (kt & 1) * 24576;
        const char* bB = aB + 8192;
        // depth-1: tile kt's loads had the whole previous phase to land.
        // vmcnt(0) drain is covered by 3-blocks/CU cross-block overlap.
        asm volatile("s_waitcnt vmcnt(0)\ns_barrier" ::: "memory");
        // refill the buffer whose reads (phase kt-1) retired before this
        // barrier (same LDS-FIFO ordering argument as r22).
        if (kt < 15) STAGE((kt + 1) & 1, kt + 1);
        {
            const int ph = (lhi ^ (llo >> 2)) << 4;
            bf16x8 aF[4], bF[4];
            #pragma unroll
            for (int mi = 0; mi < 4; ++mi)
                aF[mi] = *(const bf16x8*)(aB + (mr + mi * 16 + llo) * 64 + ph);
            #pragma unroll
            for (int ni = 0; ni < 4; ++ni)
                bF[ni] = *(const bf16x8*)(bB + (nc + ni * 16 + llo) * 64 + ph);
            __builtin_amdgcn_s_setprio(1);
            #pragma unroll
            for (int mi = 0; mi < 4; ++mi)
                #pragma unroll
                for (int ni = 0; ni < 4; ++ni)
                    acc[mi][ni] = __builtin_amdgcn_mfma_f32_16x16x32_bf16(
                        aF[mi], bF[ni], acc[mi][ni], 0, 0, 0);
            __builtin_amdgcn_s_setprio(0);
        }
    }
    __syncthreads();  // all reads done; safe to overlay eo on staging LDS

    // -------- two-pass epilogue (r16-proven): eo half [64][264] @ smem --------
    unsigned short* eoh = (unsigned short*)smem;
    #pragma unroll
    for (int pass = 0; pass < 2; ++pass) {
        __syncthreads();
        if (wr == pass) {  // waves owning rows pass*64..+63 write their acc
            #pragma unroll
            for (int ni = 0; ni < 4; ++ni) {
                const int col = nc + ni * 16 + llo;
                const float ebv = eb[n0 + col];
                #pragma unroll
                for (int mi = 0; mi < 4; ++mi)
                    #pragma unroll
                    for (int j = 0; j < 4; ++j) {
                        const int rl = mi * 16 + lhi * 4 + j;  // local row 0..63
                        eoh[rl * 264 + col] = f2bf(fmaxf(acc[mi][ni][j] + ebv, 0.f));
                    }
            }
        }
        __syncthreads();
        // contraction for rows pass*64..+63: 1024 tasks over 512 threads
        #pragma unroll
        for (int i = 0; i < 2; ++i) {
            const int f = i * 512 + tid;
            const int ml = f >> 4, ul = f & 15;
            const unsigned short* er = eoh + ml * 264 + ul * 16;
            const int brow = b0 + pass * 64 + ml;
            const float* gr = gates + (size_t)brow * 64;
            float o0 = 0.f, o1 = 0.f, o2 = 0.f, o3 = 0.f;
            #pragma unroll
            for (int e = 0; e < 16; ++e) {
                const float v = bf2f(er[e]);
                o0 = fmaf(v, gr[e], o0);
                o1 = fmaf(v, gr[16 + e], o1);
                o2 = fmaf(v, gr[32 + e], o2);
                o3 = fmaf(v, gr[48 + e], o3);
            }
            const size_t base = (size_t)brow * Uu + (n0 >> 4) + ul;
            out[base] = o0;
            out[(size_t)Bsz * Uu + base] = o1;
            out[2 * (size_t)Bsz * Uu + base] = o2;
            out[3 * (size_t)Bsz * Uu + base] = o3;
        }
    }
}

extern "C" void kernel_launch(void* const* d_in, const int* in_sizes, int n_in,
                              void* d_out, int out_size, void* d_ws, size_t ws_size,
                              hipStream_t stream) {
    const float* x  = (const float*)d_in[0];
    const float* ek = (const float*)d_in[1];
    const float* eb = (const float*)d_in[2];
    const float* gk = (const float*)d_in[3];
    const float* gb = (const float*)d_in[4];
    float* out = (float*)d_out;

    char* wsb = (char*)d_ws;
    float* gates       = (float*)wsb;                            // 4 MiB @ 0
    unsigned short* xb  = (unsigned short*)(wsb + (4u << 20));   // 16 MiB @ 4
    unsigned short* ekT = (unsigned short*)(wsb + (20u << 20));  // 2 MiB @ 20

    prep_kernel<<<1280, 256, 0, stream>>>(x, gk, gb, ek, gates, xb, ekT);
    moe_kernel<<<(Bsz / BM) * (Nn / BN), 512, 0, stream>>>(xb, ekT, eb, gates, out);
}

// Round 24
// 92.072 us; speedup vs baseline: 1.1101x; 1.1101x over previous
//
#include <hip/hip_runtime.h>

// MMoE: B=16384 D=512 U=128 E=16 T=4, fp32 in/out.
// Round 24 = ROUND-22 VERBATIM (best measured: 91.3us total, moe 57.5us).
// r23's depth-1/occupancy trade regressed (moe ~80us) -> reverted per
// pre-commitment. r22 = 128x256 tile, 8 waves, BK=32, TRIPLE-buffer 72KB
// (2 blocks/CU), counted vmcnt(3)+s_barrier per K-step, depth-2 prefetch,
// gload_lds with src/read swizzle pair, T5 setprio, r12 fused epilogue.
// prep_kernel r19 VERBATIM. ws: gates 4MiB @0, xb 16MiB @4, ekT 2MiB @20.

#define Bsz 16384
#define Dd  512
#define Uu  128
#define Ee  16
#define Tt  4
#define Nn  2048   // U*E

typedef short bf16x8 __attribute__((ext_vector_type(8)));
typedef float f32x4 __attribute__((ext_vector_type(4)));
typedef unsigned short u16x8 __attribute__((ext_vector_type(8)));

static __device__ __forceinline__ unsigned short f2bf(float f) {
    unsigned int u = __builtin_bit_cast(unsigned int, f);
    u += 0x7fffu + ((u >> 16) & 1u);   // round-to-nearest-even
    return (unsigned short)(u >> 16);
}
static __device__ __forceinline__ float bf2f(unsigned short s) {
    return __builtin_bit_cast(float, (unsigned int)s << 16);
}

#define GLOAD16(g, l) __builtin_amdgcn_global_load_lds( \
    (const __attribute__((address_space(1))) void*)(g), \
    (__attribute__((address_space(3))) void*)(l), 16, 0, 0)

// ---------------- Kernel A: prep = gates (+x->xb linear) U convert_ek ----------------
// r19 VERBATIM.
__global__ __launch_bounds__(256) void prep_kernel(
        const float* __restrict__ x, const float* __restrict__ gk,
        const float* __restrict__ gb, const float* __restrict__ ek,
        float* __restrict__ gates, unsigned short* __restrict__ xb,
        unsigned short* __restrict__ ekT) {
    __shared__ __align__(16) char pm[40960];
    const int tid = threadIdx.x;
    if (blockIdx.x >= 1024) {
        unsigned short* ts = (unsigned short*)pm;  // [64*65]
        const int b2 = blockIdx.x - 1024;
        const int n0 = (b2 & 31) * 64, d0 = (b2 >> 5) * 64;
        #pragma unroll
        for (int i = 0; i < 4; ++i) {
            int flat = i * 256 + tid;
            int dl = flat >> 4, ng = (flat & 15) * 4;
            const float4 v = *(const float4*)(ek + (size_t)(d0 + dl) * Nn + n0 + ng);
            ts[(ng + 0) * 65 + dl] = f2bf(v.x);
            ts[(ng + 1) * 65 + dl] = f2bf(v.y);
            ts[(ng + 2) * 65 + dl] = f2bf(v.z);
            ts[(ng + 3) * 65 + dl] = f2bf(v.w);
        }
        __syncthreads();
        #pragma unroll
        for (int i = 0; i < 4; ++i) {
            int flat = i * 256 + tid;
            int nl = flat >> 4, dg = (flat & 15) * 4;
            ushort4 w = make_ushort4(ts[nl * 65 + dg], ts[nl * 65 + dg + 1],
                                     ts[nl * 65 + dg + 2], ts[nl * 65 + dg + 3]);
            *(ushort4*)(ekT + (size_t)(n0 + nl) * Dd + d0 + dg) = w;
        }
        return;
    }
    float (*xl)[128] = (float (*)[128])pm;          // 8 KB
    float (*gkl)[64] = (float (*)[64])(pm + 8192);  // 32 KB
    const int w = tid >> 6, lane = tid & 63;
    const int b0 = blockIdx.x * 16;
    float acc[4] = {0.f, 0.f, 0.f, 0.f};

    for (int c = 0; c < 4; ++c) {
        const int d0 = c * 128;
        __syncthreads();  // previous chunk consumed
        #pragma unroll
        for (int p = 0; p < 2; ++p) {
            const int flat = p * 256 + tid;
            const int row = flat >> 5, c4 = (flat & 31) * 4;
            const float4 v =
                *(const float4*)(x + (size_t)(b0 + row) * Dd + d0 + c4);
            *(float4*)(&xl[row][c4]) = v;
            *(ushort4*)(xb + (size_t)(b0 + row) * Dd + d0 + c4) =
                make_ushort4(f2bf(v.x), f2bf(v.y), f2bf(v.z), f2bf(v.w));
        }
        {
            const int n = tid & 63, dl0 = tid >> 6;
            const float* gp = gk + (size_t)(n >> 4) * (Dd * Ee) + (n & 15)
                                 + (size_t)(d0 + dl0) * Ee;
            #pragma unroll
            for (int j = 0; j < 32; ++j)
                gkl[dl0 + j * 4][n] = gp[(size_t)j * 4 * Ee];
        }
        __syncthreads();
        #pragma unroll 4
        for (int dq = 0; dq < 32; ++dq) {
            float wv[4];
            #pragma unroll
            for (int q = 0; q < 4; ++q) wv[q] = gkl[dq * 4 + q][lane];
            #pragma unroll
            for (int r = 0; r < 4; ++r) {
                const float4 xv = *(const float4*)(&xl[w * 4 + r][dq * 4]);
                float a = acc[r];
                a = fmaf(xv.x, wv[0], a);
                a = fmaf(xv.y, wv[1], a);
                a = fmaf(xv.z, wv[2], a);
                a = fmaf(xv.w, wv[3], a);
                acc[r] = a;
            }
        }
    }
    const float bias = gb[lane];
    #pragma unroll
    for (int r = 0; r < 4; ++r) {
        float a = acc[r] + bias;
        float m = a;
        m = fmaxf(m, __shfl_xor(m, 1));
        m = fmaxf(m, __shfl_xor(m, 2));
        m = fmaxf(m, __shfl_xor(m, 4));
        m = fmaxf(m, __shfl_xor(m, 8));
        float p = __expf(a - m);
        float s = p;
        s += __shfl_xor(s, 1);
        s += __shfl_xor(s, 2);
        s += __shfl_xor(s, 4);
        s += __shfl_xor(s, 8);
        gates[(size_t)(b0 + w * 4 + r) * 64 + lane] = p / s;  // [b][t*16+e]
    }
}

// ---------------- Kernel B: expert GEMM + relu + gate contraction ----------------
// 128x256, 8 waves, BK=32, triple-buffer 72KB, counted vmcnt(3), gload_lds.
#define BM 128
#define BN 256
#define BK 32

// src pre-swizzle (r18/r22-PASSED pair): phys chunk p of row r holds logical
// chunk l = p ^ ((r>>2)&3); read uses ph = (lhi ^ (llo>>2))<<4.
#define ST_A(buf, kt_) {                                                        \
    const int c_ = wave * 64 + lane;                                            \
    const int r_ = c_ >> 2;                                                     \
    const int l_ = (c_ & 3) ^ ((r_ >> 2) & 3);                                  \
    GLOAD16(xb + (size_t)(b0 + r_) * Dd + (kt_) * BK + l_ * 8,                  \
            smem + (buf) * 24576 + c_ * 16); }
#define ST_B(buf, kt_) { _Pragma("unroll")                                      \
    for (int i_ = 0; i_ < 2; ++i_) {                                            \
        const int c_ = i_ * 512 + wave * 64 + lane;                             \
        const int r_ = c_ >> 2;                                                 \
        const int l_ = (c_ & 3) ^ ((r_ >> 2) & 3);                              \
        GLOAD16(ekT + (size_t)(n0 + r_) * Dd + (kt_) * BK + l_ * 8,             \
                smem + (buf) * 24576 + 8192 + c_ * 16); } }
#define STAGE(buf, kt_) { ST_A(buf, kt_) ST_B(buf, kt_) }  // 3 loads/wave

__global__ __launch_bounds__(512) void moe_kernel(
        const unsigned short* __restrict__ xb,
        const unsigned short* __restrict__ ekT,
        const float* __restrict__ eb, const float* __restrict__ gates,
        float* __restrict__ out) {
    __shared__ __align__(64) char smem[73728];  // 3 bufs x (A 8K + B 16K)
    const int tid = threadIdx.x;
    const int wave = tid >> 6, lane = tid & 63;
    const int llo = lane & 15, lhi = lane >> 4;
    const int g = (blockIdx.x & 7) * 128 + (blockIdx.x >> 3);  // XCD swizzle
    const int b0 = (g >> 3) * BM;
    const int n0 = (g & 7) * BN;
    const int mr = (wave >> 2) * 64, nc = (wave & 3) * 64;
    f32x4 acc[4][4] = {};

    STAGE(0, 0);
    STAGE(1, 1);
    for (int kt = 0; kt < Dd / BK; ++kt) {
        const char* aB = smem + (kt % 3) * 24576;
        const char* bB = aB + 8192;
        // counted wait: own 3 oldest loads (tile kt) drain; tile kt+1's 3
        // stay in flight across the barrier. Barrier publishes to all waves.
        if (kt < 15) asm volatile("s_waitcnt vmcnt(3)\ns_barrier" ::: "memory");
        else         asm volatile("s_waitcnt vmcnt(0)\ns_barrier" ::: "memory");
        if (kt < 14) STAGE((kt + 2) % 3, kt + 2);  // buf last read in kt-1
        {
            const int ph = (lhi ^ (llo >> 2)) << 4;
            bf16x8 aF[4], bF[4];
            #pragma unroll
            for (int mi = 0; mi < 4; ++mi)
                aF[mi] = *(const bf16x8*)(aB + (mr + mi * 16 + llo) * 64 + ph);
            #pragma unroll
            for (int ni = 0; ni < 4; ++ni)
                bF[ni] = *(const bf16x8*)(bB + (nc + ni * 16 + llo) * 64 + ph);
            __builtin_amdgcn_s_setprio(1);
            #pragma unroll
            for (int mi = 0; mi < 4; ++mi)
                #pragma unroll
                for (int ni = 0; ni < 4; ++ni)
                    acc[mi][ni] = __builtin_amdgcn_mfma_f32_16x16x32_bf16(
                        aF[mi], bF[ni], acc[mi][ni], 0, 0, 0);
            __builtin_amdgcn_s_setprio(0);
        }
    }
    __syncthreads();  // all reads done; safe to overlay eo on staging LDS

    // -------- epilogue: r12 VERBATIM (eo [128][264] overlay, fused contraction) --------
    unsigned short* eo = (unsigned short*)smem;
    #pragma unroll
    for (int ni = 0; ni < 4; ++ni) {
        const int col = nc + ni * 16 + llo;
        const float ebv = eb[n0 + col];
        #pragma unroll
        for (int mi = 0; mi < 4; ++mi) {
            #pragma unroll
            for (int j = 0; j < 4; ++j) {
                int row = mr + mi * 16 + lhi * 4 + j;
                eo[row * 264 + col] = f2bf(fmaxf(acc[mi][ni][j] + ebv, 0.f));
            }
        }
    }
    __syncthreads();
    #pragma unroll
    for (int i = 0; i < 4; ++i) {
        int f = i * 512 + tid;
        int m = f >> 4, ul = f & 15;
        const unsigned short* er = eo + m * 264 + ul * 16;
        const float* gr = gates + (size_t)(b0 + m) * 64;
        float o0 = 0.f, o1 = 0.f, o2 = 0.f, o3 = 0.f;
        #pragma unroll
        for (int e = 0; e < 16; ++e) {
            float v = bf2f(er[e]);
            o0 = fmaf(v, gr[e], o0);
            o1 = fmaf(v, gr[16 + e], o1);
            o2 = fmaf(v, gr[32 + e], o2);
            o3 = fmaf(v, gr[48 + e], o3);
        }
        size_t base = (size_t)(b0 + m) * Uu + (n0 >> 4) + ul;
        out[base] = o0;
        out[(size_t)Bsz * Uu + base] = o1;
        out[2 * (size_t)Bsz * Uu + base] = o2;
        out[3 * (size_t)Bsz * Uu + base] = o3;
    }
}

extern "C" void kernel_launch(void* const* d_in, const int* in_sizes, int n_in,
                              void* d_out, int out_size, void* d_ws, size_t ws_size,
                              hipStream_t stream) {
    const float* x  = (const float*)d_in[0];
    const float* ek = (const float*)d_in[1];
    const float* eb = (const float*)d_in[2];
    const float* gk = (const float*)d_in[3];
    const float* gb = (const float*)d_in[4];
    float* out = (float*)d_out;

    char* wsb = (char*)d_ws;
    float* gates       = (float*)wsb;                            // 4 MiB @ 0
    unsigned short* xb  = (unsigned short*)(wsb + (4u << 20));   // 16 MiB @ 4
    unsigned short* ekT = (unsigned short*)(wsb + (20u << 20));  // 2 MiB @ 20

    prep_kernel<<<1280, 256, 0, stream>>>(x, gk, gb, ek, gates, xb, ekT);
    moe_kernel<<<(Bsz / BM) * (Nn / BN), 512, 0, stream>>>(xb, ekT, eb, gates, out);
}

// Round 25
// 83.966 us; speedup vs baseline: 1.2173x; 1.0965x over previous
//
#include <hip/hip_runtime.h>

// MMoE: B=16384 D=512 U=128 E=16 T=4, fp32 in/out.
// vs r24 (PASSING, 92.1us = r22 anchor): ONE change — prep's gates section
// replaced by hi/lo bf16 MFMA gates (r2 technique, exonerated by r19's
// epilogue-bug finding). 3 MFMAs per frag (ah*bh+al*bh+ah*bl) ~= f32 logits
// (err ~1e-4 << 0.0156 floor). xb emission fused (hi part == f2bf(x), bits
// identical). gk gathered from L2 per block (no extra ws). Softmax shuffle +
// [b][t*16+e] layout unchanged. moe_kernel: r22/r24 VERBATIM.
// ws: gates 4MiB @0, xb 16MiB @4, ekT 2MiB @20.

#define Bsz 16384
#define Dd  512
#define Uu  128
#define Ee  16
#define Tt  4
#define Nn  2048   // U*E

typedef short bf16x8 __attribute__((ext_vector_type(8)));
typedef float f32x4 __attribute__((ext_vector_type(4)));
typedef unsigned short u16x8 __attribute__((ext_vector_type(8)));

static __device__ __forceinline__ unsigned short f2bf(float f) {
    unsigned int u = __builtin_bit_cast(unsigned int, f);
    u += 0x7fffu + ((u >> 16) & 1u);   // round-to-nearest-even
    return (unsigned short)(u >> 16);
}
static __device__ __forceinline__ float bf2f(unsigned short s) {
    return __builtin_bit_cast(float, (unsigned int)s << 16);
}

#define GLOAD16(g, l) __builtin_amdgcn_global_load_lds( \
    (const __attribute__((address_space(1))) void*)(g), \
    (__attribute__((address_space(3))) void*)(l), 16, 0, 0)

// ---------------- Kernel A: prep = MFMA-gates (+x->xb) U convert_ek ----------------
// blocks [0,256): gates, 64 rows/block, hi/lo bf16 MFMA + fused xb emission.
// blocks [256,512): ek [512][2048] -> ekT [2048][512] bf16 (r19 verbatim).
#define GLD 72  // padded LDS row stride (shorts); 144B, 16B-aligned
__global__ __launch_bounds__(256) void prep_kernel(
        const float* __restrict__ x, const float* __restrict__ gk,
        const float* __restrict__ gb, const float* __restrict__ ek,
        float* __restrict__ gates, unsigned short* __restrict__ xb,
        unsigned short* __restrict__ ekT) {
    __shared__ __align__(16) unsigned short pm[4 * 64 * GLD];  // 36864 B
    const int tid = threadIdx.x;
    if (blockIdx.x >= 256) {
        unsigned short* ts = pm;  // [64*65]
        const int b2 = blockIdx.x - 256;
        const int n0 = (b2 & 31) * 64, d0 = (b2 >> 5) * 64;
        #pragma unroll
        for (int i = 0; i < 4; ++i) {
            int flat = i * 256 + tid;
            int dl = flat >> 4, ng = (flat & 15) * 4;
            const float4 v = *(const float4*)(ek + (size_t)(d0 + dl) * Nn + n0 + ng);
            ts[(ng + 0) * 65 + dl] = f2bf(v.x);
            ts[(ng + 1) * 65 + dl] = f2bf(v.y);
            ts[(ng + 2) * 65 + dl] = f2bf(v.z);
            ts[(ng + 3) * 65 + dl] = f2bf(v.w);
        }
        __syncthreads();
        #pragma unroll
        for (int i = 0; i < 4; ++i) {
            int flat = i * 256 + tid;
            int nl = flat >> 4, dg = (flat & 15) * 4;
            ushort4 w = make_ushort4(ts[nl * 65 + dg], ts[nl * 65 + dg + 1],
                                     ts[nl * 65 + dg + 2], ts[nl * 65 + dg + 3]);
            *(ushort4*)(ekT + (size_t)(n0 + nl) * Dd + d0 + dg) = w;
        }
        return;
    }
    // ---- gates: 64 rows, 4 waves; wave w -> output rows w*16..+15, all 64 n ----
    unsigned short* sAh = pm;                 // [64][GLD]
    unsigned short* sAl = pm + 64 * GLD;
    unsigned short* sBh = pm + 2 * 64 * GLD;  // [n][GLD] (n = t*16+e)
    unsigned short* sBl = pm + 3 * 64 * GLD;
    const int w = tid >> 6, lane = tid & 63;
    const int llo = lane & 15, lhi = lane >> 4;
    const int b0 = blockIdx.x * 64;
    const int n = lane;                 // for gk staging: n = t*16+e
    const int gt = n >> 4, ge = n & 15;
    f32x4 acc[4] = {};

    for (int c = 0; c < 8; ++c) {
        const int d0 = c * 64;
        __syncthreads();  // previous chunk consumed
        // stage x 64rows x 64d: split hi/lo; hi ushort4 also -> xb (== f2bf(x))
        #pragma unroll
        for (int p = 0; p < 4; ++p) {
            const int flat = p * 256 + tid;
            const int row = flat >> 4, c4 = (flat & 15) * 4;
            const float4 v = *(const float4*)(x + (size_t)(b0 + row) * Dd + d0 + c4);
            unsigned short h0 = f2bf(v.x), h1 = f2bf(v.y), h2 = f2bf(v.z), h3 = f2bf(v.w);
            const ushort4 hv = make_ushort4(h0, h1, h2, h3);
            *(ushort4*)(sAh + row * GLD + c4) = hv;
            *(ushort4*)(sAl + row * GLD + c4) = make_ushort4(
                f2bf(v.x - bf2f(h0)), f2bf(v.y - bf2f(h1)),
                f2bf(v.z - bf2f(h2)), f2bf(v.w - bf2f(h3)));
            *(ushort4*)(xb + (size_t)(b0 + row) * Dd + d0 + c4) = hv;
        }
        // stage gk row n: 16 d's per thread (4 x ushort4), gathered from L2
        {
            const float* gkb = gk + (size_t)gt * (Dd * Ee) + ge;
            #pragma unroll
            for (int jj = 0; jj < 4; ++jj) {
                const int dql = (tid >> 6) * 4 + jj;      // 16B slot 0..15
                const int d = d0 + dql * 4;
                float v0 = gkb[(size_t)(d + 0) * Ee];
                float v1 = gkb[(size_t)(d + 1) * Ee];
                float v2 = gkb[(size_t)(d + 2) * Ee];
                float v3 = gkb[(size_t)(d + 3) * Ee];
                unsigned short h0 = f2bf(v0), h1 = f2bf(v1), h2 = f2bf(v2), h3 = f2bf(v3);
                *(ushort4*)(sBh + n * GLD + dql * 4) = make_ushort4(h0, h1, h2, h3);
                *(ushort4*)(sBl + n * GLD + dql * 4) = make_ushort4(
                    f2bf(v0 - bf2f(h0)), f2bf(v1 - bf2f(h1)),
                    f2bf(v2 - bf2f(h2)), f2bf(v3 - bf2f(h3)));
            }
        }
        __syncthreads();
        #pragma unroll
        for (int ks = 0; ks < 64; ks += 32) {
            const bf16x8 ah = *(const bf16x8*)(sAh + (w * 16 + llo) * GLD + ks + lhi * 8);
            const bf16x8 al = *(const bf16x8*)(sAl + (w * 16 + llo) * GLD + ks + lhi * 8);
            #pragma unroll
            for (int ni = 0; ni < 4; ++ni) {
                const bf16x8 bh = *(const bf16x8*)(sBh + (ni * 16 + llo) * GLD + ks + lhi * 8);
                const bf16x8 bl = *(const bf16x8*)(sBl + (ni * 16 + llo) * GLD + ks + lhi * 8);
                acc[ni] = __builtin_amdgcn_mfma_f32_16x16x32_bf16(ah, bh, acc[ni], 0, 0, 0);
                acc[ni] = __builtin_amdgcn_mfma_f32_16x16x32_bf16(al, bh, acc[ni], 0, 0, 0);
                acc[ni] = __builtin_amdgcn_mfma_f32_16x16x32_bf16(ah, bl, acc[ni], 0, 0, 0);
            }
        }
    }
    // softmax over e (= llo lanes) per task t (= ni); store gates[b][t*16+e]
    #pragma unroll
    for (int ni = 0; ni < 4; ++ni) {
        const float bias = gb[ni * 16 + llo];
        #pragma unroll
        for (int j = 0; j < 4; ++j) {
            float lg = acc[ni][j] + bias;
            float m = lg;
            m = fmaxf(m, __shfl_xor(m, 1));
            m = fmaxf(m, __shfl_xor(m, 2));
            m = fmaxf(m, __shfl_xor(m, 4));
            m = fmaxf(m, __shfl_xor(m, 8));
            float p = __expf(lg - m);
            float s = p;
            s += __shfl_xor(s, 1);
            s += __shfl_xor(s, 2);
            s += __shfl_xor(s, 4);
            s += __shfl_xor(s, 8);
            const int row = b0 + w * 16 + lhi * 4 + j;  // C frag: row=(lane>>4)*4+j
            gates[(size_t)row * 64 + ni * 16 + llo] = p / s;
        }
    }
}

// ---------------- Kernel B: expert GEMM + relu + gate contraction ----------------
// r22/r24 VERBATIM: 128x256, 8 waves, BK=32, triple-buffer 72KB, vmcnt(3).
#define BM 128
#define BN 256
#define BK 32

#define ST_A(buf, kt_) {                                                        \
    const int c_ = wave * 64 + lane;                                            \
    const int r_ = c_ >> 2;                                                     \
    const int l_ = (c_ & 3) ^ ((r_ >> 2) & 3);                                  \
    GLOAD16(xb + (size_t)(b0 + r_) * Dd + (kt_) * BK + l_ * 8,                  \
            smem + (buf) * 24576 + c_ * 16); }
#define ST_B(buf, kt_) { _Pragma("unroll")                                      \
    for (int i_ = 0; i_ < 2; ++i_) {                                            \
        const int c_ = i_ * 512 + wave * 64 + lane;                             \
        const int r_ = c_ >> 2;                                                 \
        const int l_ = (c_ & 3) ^ ((r_ >> 2) & 3);                              \
        GLOAD16(ekT + (size_t)(n0 + r_) * Dd + (kt_) * BK + l_ * 8,             \
                smem + (buf) * 24576 + 8192 + c_ * 16); } }
#define STAGE(buf, kt_) { ST_A(buf, kt_) ST_B(buf, kt_) }  // 3 loads/wave

__global__ __launch_bounds__(512) void moe_kernel(
        const unsigned short* __restrict__ xb,
        const unsigned short* __restrict__ ekT,
        const float* __restrict__ eb, const float* __restrict__ gates,
        float* __restrict__ out) {
    __shared__ __align__(64) char smem[73728];  // 3 bufs x (A 8K + B 16K)
    const int tid = threadIdx.x;
    const int wave = tid >> 6, lane = tid & 63;
    const int llo = lane & 15, lhi = lane >> 4;
    const int g = (blockIdx.x & 7) * 128 + (blockIdx.x >> 3);  // XCD swizzle
    const int b0 = (g >> 3) * BM;
    const int n0 = (g & 7) * BN;
    const int mr = (wave >> 2) * 64, nc = (wave & 3) * 64;
    f32x4 acc[4][4] = {};

    STAGE(0, 0);
    STAGE(1, 1);
    for (int kt = 0; kt < Dd / BK; ++kt) {
        const char* aB = smem + (kt % 3) * 24576;
        const char* bB = aB + 8192;
        if (kt < 15) asm volatile("s_waitcnt vmcnt(3)\ns_barrier" ::: "memory");
        else         asm volatile("s_waitcnt vmcnt(0)\ns_barrier" ::: "memory");
        if (kt < 14) STAGE((kt + 2) % 3, kt + 2);  // buf last read in kt-1
        {
            const int ph = (lhi ^ (llo >> 2)) << 4;
            bf16x8 aF[4], bF[4];
            #pragma unroll
            for (int mi = 0; mi < 4; ++mi)
                aF[mi] = *(const bf16x8*)(aB + (mr + mi * 16 + llo) * 64 + ph);
            #pragma unroll
            for (int ni = 0; ni < 4; ++ni)
                bF[ni] = *(const bf16x8*)(bB + (nc + ni * 16 + llo) * 64 + ph);
            __builtin_amdgcn_s_setprio(1);
            #pragma unroll
            for (int mi = 0; mi < 4; ++mi)
                #pragma unroll
                for (int ni = 0; ni < 4; ++ni)
                    acc[mi][ni] = __builtin_amdgcn_mfma_f32_16x16x32_bf16(
                        aF[mi], bF[ni], acc[mi][ni], 0, 0, 0);
            __builtin_amdgcn_s_setprio(0);
        }
    }
    __syncthreads();  // all reads done; safe to overlay eo on staging LDS

    unsigned short* eo = (unsigned short*)smem;
    #pragma unroll
    for (int ni = 0; ni < 4; ++ni) {
        const int col = nc + ni * 16 + llo;
        const float ebv = eb[n0 + col];
        #pragma unroll
        for (int mi = 0; mi < 4; ++mi) {
            #pragma unroll
            for (int j = 0; j < 4; ++j) {
                int row = mr + mi * 16 + lhi * 4 + j;
                eo[row * 264 + col] = f2bf(fmaxf(acc[mi][ni][j] + ebv, 0.f));
            }
        }
    }
    __syncthreads();
    #pragma unroll
    for (int i = 0; i < 4; ++i) {
        int f = i * 512 + tid;
        int m = f >> 4, ul = f & 15;
        const unsigned short* er = eo + m * 264 + ul * 16;
        const float* gr = gates + (size_t)(b0 + m) * 64;
        float o0 = 0.f, o1 = 0.f, o2 = 0.f, o3 = 0.f;
        #pragma unroll
        for (int e = 0; e < 16; ++e) {
            float v = bf2f(er[e]);
            o0 = fmaf(v, gr[e], o0);
            o1 = fmaf(v, gr[16 + e], o1);
            o2 = fmaf(v, gr[32 + e], o2);
            o3 = fmaf(v, gr[48 + e], o3);
        }
        size_t base = (size_t)(b0 + m) * Uu + (n0 >> 4) + ul;
        out[base] = o0;
        out[(size_t)Bsz * Uu + base] = o1;
        out[2 * (size_t)Bsz * Uu + base] = o2;
        out[3 * (size_t)Bsz * Uu + base] = o3;
    }
}

extern "C" void kernel_launch(void* const* d_in, const int* in_sizes, int n_in,
                              void* d_out, int out_size, void* d_ws, size_t ws_size,
                              hipStream_t stream) {
    const float* x  = (const float*)d_in[0];
    const float* ek = (const float*)d_in[1];
    const float* eb = (const float*)d_in[2];
    const float* gk = (const float*)d_in[3];
    const float* gb = (const float*)d_in[4];
    float* out = (float*)d_out;

    char* wsb = (char*)d_ws;
    float* gates       = (float*)wsb;                            // 4 MiB @ 0
    unsigned short* xb  = (unsigned short*)(wsb + (4u << 20));   // 16 MiB @ 4
    unsigned short* ekT = (unsigned short*)(wsb + (20u << 20));  // 2 MiB @ 20

    prep_kernel<<<512, 256, 0, stream>>>(x, gk, gb, ek, gates, xb, ekT);
    moe_kernel<<<(Bsz / BM) * (Nn / BN), 512, 0, stream>>>(xb, ekT, eb, gates, out);
}